// Round 1
// baseline (1240.383 us; speedup 1.0000x reference)
//
#include <hip/hip_runtime.h>

#define DD 128

typedef _Float16 f16;

static inline int cdiv(int a, int b) { return (a + b - 1) / b; }

// ---------------- CSR build ----------------

__global__ __launch_bounds__(256) void count_kernel(const int* __restrict__ dst, int E,
                                                    int* __restrict__ cnt) {
    int e = blockIdx.x * 256 + threadIdx.x;
    if (e < E) atomicAdd(&cnt[dst[e]], 1);
}

__global__ __launch_bounds__(256) void scan1(const int* __restrict__ cnt, int N,
                                             int* __restrict__ bsum) {
    __shared__ int s[256];
    int i = blockIdx.x * 256 + threadIdx.x;
    s[threadIdx.x] = (i < N) ? cnt[i] : 0;
    __syncthreads();
    for (int off = 128; off > 0; off >>= 1) {
        if (threadIdx.x < off) s[threadIdx.x] += s[threadIdx.x + off];
        __syncthreads();
    }
    if (threadIdx.x == 0) bsum[blockIdx.x] = s[0];
}

__global__ __launch_bounds__(512) void scan2(const int* __restrict__ bsum, int NB,
                                             int* __restrict__ boff) {
    __shared__ int s[512];
    int t = threadIdx.x;
    int v = (t < NB) ? bsum[t] : 0;
    s[t] = v;
    __syncthreads();
    for (int off = 1; off < 512; off <<= 1) {
        int x = (t >= off) ? s[t - off] : 0;
        __syncthreads();
        s[t] += x;
        __syncthreads();
    }
    if (t < NB) boff[t] = s[t] - v;  // exclusive
}

__global__ __launch_bounds__(256) void scan3(const int* __restrict__ cnt,
                                             const int* __restrict__ boff, int N,
                                             int* __restrict__ off) {
    __shared__ int s[256];
    int t = threadIdx.x;
    int i = blockIdx.x * 256 + t;
    int v = (i < N) ? cnt[i] : 0;
    s[t] = v;
    __syncthreads();
    for (int o = 1; o < 256; o <<= 1) {
        int x = (t >= o) ? s[t - o] : 0;
        __syncthreads();
        s[t] += x;
        __syncthreads();
    }
    int excl = s[t] - v + boff[blockIdx.x];
    if (i < N) off[i] = excl;
    if (i == N - 1) off[N] = excl + v;
}

__global__ __launch_bounds__(256) void fill_kernel(const int* __restrict__ src,
                                                   const int* __restrict__ dst, int E,
                                                   const int* __restrict__ off,
                                                   int* __restrict__ cnt,
                                                   int* __restrict__ csr) {
    int e = blockIdx.x * 256 + threadIdx.x;
    if (e < E) {
        int d = dst[e];
        int p = atomicSub(&cnt[d], 1) - 1;  // unique slot within [0, deg)
        csr[off[d] + p] = src[e];
    }
}

// ---------------- aggregation (mean of gathered h rows) ----------------

__global__ __launch_bounds__(256) void aggregate_kernel(const f16* __restrict__ h,
                                                        const int* __restrict__ off,
                                                        const int* __restrict__ csr,
                                                        f16* __restrict__ mean, int N) {
    int n = blockIdx.x * 2 + (threadIdx.x >> 7);
    int d = threadIdx.x & 127;
    if (n >= N) return;
    int s = off[n], e = off[n + 1];
    float acc = 0.f;
    for (int i = s; i < e; ++i) {
        int sc = csr[i];
        acc += (float)h[sc * DD + d];
    }
    int deg = e - s;
    float inv = 1.0f / (float)(deg > 0 ? deg : 1);
    mean[n * DD + d] = (f16)(acc * inv);
}

// ---------------- tiled GEMM: OUT = act(A @ W1^T + bias [+ B @ W2^T]) ----------------
// A,B: [M,128] (TA/TB), W: [128,128] row-major (use W[j][k]), OUT: [M,128] (TO)

template <typename T>
__device__ inline void gemm_pass(const T* __restrict__ A, const float* __restrict__ W,
                                 float (&acc)[4][8], float (*As)[33], float (*Ws)[129],
                                 int row0, int M, int t, int tx, int ty) {
    for (int k0 = 0; k0 < DD; k0 += 32) {
        __syncthreads();  // protect LDS reuse from previous iteration
#pragma unroll
        for (int r = 0; r < 8; ++r) {  // 64x32 A tile
            int idx = t + r * 256;
            int ar = idx >> 5, ac = idx & 31;
            int g = row0 + ar;
            As[ar][ac] = (g < M) ? (float)A[g * DD + k0 + ac] : 0.f;
        }
#pragma unroll
        for (int r = 0; r < 16; ++r) {  // 128x32 W tile, stored transposed: Ws[k][j]
            int idx = t + r * 256;
            int j = idx >> 5, c = idx & 31;
            Ws[c][j] = W[j * DD + k0 + c];
        }
        __syncthreads();
#pragma unroll
        for (int kk = 0; kk < 32; ++kk) {
            float a0 = As[ty * 4 + 0][kk];
            float a1 = As[ty * 4 + 1][kk];
            float a2 = As[ty * 4 + 2][kk];
            float a3 = As[ty * 4 + 3][kk];
            float w[8];
#pragma unroll
            for (int c = 0; c < 8; ++c) w[c] = Ws[kk][tx * 8 + c];
#pragma unroll
            for (int c = 0; c < 8; ++c) {
                acc[0][c] += a0 * w[c];
                acc[1][c] += a1 * w[c];
                acc[2][c] += a2 * w[c];
                acc[3][c] += a3 * w[c];
            }
        }
    }
}

template <typename TA, typename TB, typename TO, bool RELU, bool HASB>
__global__ __launch_bounds__(256) void gemm_kernel(const TA* __restrict__ A,
                                                   const float* __restrict__ W1,
                                                   const float* __restrict__ bias,
                                                   const TB* __restrict__ B,
                                                   const float* __restrict__ W2,
                                                   TO* __restrict__ OUT, int M) {
    __shared__ float As[64][33];
    __shared__ float Ws[32][129];
    int t = threadIdx.x, tx = t & 15, ty = t >> 4;
    int row0 = blockIdx.x * 64;
    float acc[4][8];
#pragma unroll
    for (int r = 0; r < 4; ++r)
#pragma unroll
        for (int c = 0; c < 8; ++c) acc[r][c] = bias[tx * 8 + c];
    gemm_pass(A, W1, acc, As, Ws, row0, M, t, tx, ty);
    if constexpr (HASB) gemm_pass(B, W2, acc, As, Ws, row0, M, t, tx, ty);
#pragma unroll
    for (int r = 0; r < 4; ++r) {
        int g = row0 + ty * 4 + r;
        if (g < M) {
#pragma unroll
            for (int c = 0; c < 8; ++c) {
                float v = acc[r][c];
                if (RELU) v = fmaxf(v, 0.f);
                OUT[g * DD + tx * 8 + c] = (TO)v;
            }
        }
    }
}

// ---------------- launch ----------------

extern "C" void kernel_launch(void* const* d_in, const int* in_sizes, int n_in,
                              void* d_out, int out_size, void* d_ws, size_t ws_size,
                              hipStream_t stream) {
    const float* x = (const float*)d_in[0];
    const int* ei = (const int*)d_in[1];
    const float* Wp0 = (const float*)d_in[2];
    const float* bp0 = (const float*)d_in[3];
    const float* Wl0 = (const float*)d_in[4];
    const float* bl0 = (const float*)d_in[5];
    const float* Wr0 = (const float*)d_in[6];
    const float* Wp1 = (const float*)d_in[7];
    const float* bp1 = (const float*)d_in[8];
    const float* Wl1 = (const float*)d_in[9];
    const float* bl1 = (const float*)d_in[10];
    const float* Wr1 = (const float*)d_in[11];

    int N = in_sizes[0] / DD;
    int E = in_sizes[1] / 2;
    const int* src = ei;
    const int* dst = ei + E;

    char* ws = (char*)d_ws;
    size_t o = 0;
    auto alloc = [&](size_t bytes) {
        size_t r = o;
        o = (o + bytes + 255) & ~(size_t)255;
        return r;
    };
    f16* h = (f16*)(ws + alloc((size_t)N * DD * 2));
    f16* mean = (f16*)(ws + alloc((size_t)N * DD * 2));
    f16* y1 = (f16*)(ws + alloc((size_t)N * DD * 2));
    int* cnt = (int*)(ws + alloc((size_t)N * 4));
    int* off = (int*)(ws + alloc((size_t)(N + 1) * 4));
    int NB = cdiv(N, 256);
    int* bsum = (int*)(ws + alloc((size_t)NB * 4));
    int* boff = (int*)(ws + alloc((size_t)NB * 4));
    int* csr = (int*)(ws + alloc((size_t)E * 4));
    (void)ws_size;

    // CSR build (shared by both layers)
    hipMemsetAsync(cnt, 0, (size_t)N * 4, stream);
    count_kernel<<<cdiv(E, 256), 256, 0, stream>>>(dst, E, cnt);
    scan1<<<NB, 256, 0, stream>>>(cnt, N, bsum);
    scan2<<<1, 512, 0, stream>>>(bsum, NB, boff);
    scan3<<<NB, 256, 0, stream>>>(cnt, boff, N, off);
    fill_kernel<<<cdiv(E, 256), 256, 0, stream>>>(src, dst, E, off, cnt, csr);

    int GB = cdiv(N, 64);
    // layer 1
    gemm_kernel<float, float, f16, true, false>
        <<<GB, 256, 0, stream>>>(x, Wp0, bp0, nullptr, nullptr, h, N);
    aggregate_kernel<<<cdiv(N, 2), 256, 0, stream>>>(h, off, csr, mean, N);
    gemm_kernel<f16, float, f16, true, true>
        <<<GB, 256, 0, stream>>>(mean, Wl0, bl0, x, Wr0, y1, N);
    // layer 2
    gemm_kernel<f16, f16, f16, true, false>
        <<<GB, 256, 0, stream>>>(y1, Wp1, bp1, nullptr, nullptr, h, N);
    aggregate_kernel<<<cdiv(N, 2), 256, 0, stream>>>(h, off, csr, mean, N);
    gemm_kernel<f16, f16, float, false, true>
        <<<GB, 256, 0, stream>>>(mean, Wl1, bl1, y1, Wr1, (float*)d_out, N);
}

// Round 3
// 295.919 us; speedup vs baseline: 4.1916x; 4.1916x over previous
//
#include <hip/hip_runtime.h>

#define DD 128

typedef _Float16 f16;
typedef __attribute__((ext_vector_type(8))) _Float16 v8h;
typedef __attribute__((ext_vector_type(4))) _Float16 v4h;
typedef __attribute__((ext_vector_type(2))) _Float16 f16x2;
typedef __attribute__((ext_vector_type(4))) float f32x4;

static inline int cdiv(int a, int b) { return (a + b - 1) / b; }

// ---------------- small utility ----------------

__global__ __launch_bounds__(256) void zero_kernel(int* __restrict__ p, int n) {
    int i = blockIdx.x * 256 + threadIdx.x;
    if (i < n) p[i] = 0;
}

// ---------------- CSR build ----------------

__global__ __launch_bounds__(256) void count_kernel(const int* __restrict__ dst, int E,
                                                    int* __restrict__ cnt) {
    int e = blockIdx.x * 256 + threadIdx.x;
    if (e < E) atomicAdd(&cnt[dst[e]], 1);
}

__global__ __launch_bounds__(256) void scan1(const int* __restrict__ cnt, int N,
                                             int* __restrict__ bsum) {
    __shared__ int s[256];
    int i = blockIdx.x * 256 + threadIdx.x;
    s[threadIdx.x] = (i < N) ? cnt[i] : 0;
    __syncthreads();
    for (int off = 128; off > 0; off >>= 1) {
        if (threadIdx.x < off) s[threadIdx.x] += s[threadIdx.x + off];
        __syncthreads();
    }
    if (threadIdx.x == 0) bsum[blockIdx.x] = s[0];
}

__global__ __launch_bounds__(512) void scan2(const int* __restrict__ bsum, int NB,
                                             int* __restrict__ boff) {
    __shared__ int s[512];
    int t = threadIdx.x;
    int v = (t < NB) ? bsum[t] : 0;
    s[t] = v;
    __syncthreads();
    for (int off = 1; off < 512; off <<= 1) {
        int x = (t >= off) ? s[t - off] : 0;
        __syncthreads();
        s[t] += x;
        __syncthreads();
    }
    if (t < NB) boff[t] = s[t] - v;  // exclusive
}

__global__ __launch_bounds__(256) void scan3(const int* __restrict__ cnt,
                                             const int* __restrict__ boff, int N,
                                             int* __restrict__ off) {
    __shared__ int s[256];
    int t = threadIdx.x;
    int i = blockIdx.x * 256 + t;
    int v = (i < N) ? cnt[i] : 0;
    s[t] = v;
    __syncthreads();
    for (int o = 1; o < 256; o <<= 1) {
        int x = (t >= o) ? s[t - o] : 0;
        __syncthreads();
        s[t] += x;
        __syncthreads();
    }
    int excl = s[t] - v + boff[blockIdx.x];
    if (i < N) off[i] = excl;
    if (i == N - 1) off[N] = excl + v;
}

__global__ __launch_bounds__(256) void fill_kernel(const int* __restrict__ src,
                                                   const int* __restrict__ dst, int E,
                                                   const int* __restrict__ off,
                                                   int* __restrict__ cnt,
                                                   int* __restrict__ csr) {
    int e = blockIdx.x * 256 + threadIdx.x;
    if (e < E) {
        int d = dst[e];
        int p = atomicSub(&cnt[d], 1) - 1;  // unique slot within [0, deg)
        csr[off[d] + p] = src[e];
    }
}

// ---------------- weight fp32 -> f16 conversion (6 matrices of 128x128) ----------------

__global__ __launch_bounds__(256) void cvt_w_kernel(const float* __restrict__ W0,
                                                    const float* __restrict__ W1,
                                                    const float* __restrict__ W2,
                                                    const float* __restrict__ W3,
                                                    const float* __restrict__ W4,
                                                    const float* __restrict__ W5,
                                                    f16* __restrict__ out) {
    int mat = blockIdx.x >> 4;  // 16 blocks per matrix (16384 elems / (256*4))
    const float* W = mat == 0 ? W0 : mat == 1 ? W1 : mat == 2 ? W2
                   : mat == 3 ? W3 : mat == 4 ? W4 : W5;
    int base = (blockIdx.x & 15) * 1024 + threadIdx.x * 4;
    float4 v = *(const float4*)(W + base);
    v4h o;
    o[0] = (f16)v.x; o[1] = (f16)v.y; o[2] = (f16)v.z; o[3] = (f16)v.w;
    *(v4h*)(out + mat * 16384 + base) = o;
}

// ---------------- aggregation: mean of gathered h rows (wave per node) ----------------

__global__ __launch_bounds__(256) void aggregate_kernel(const f16* __restrict__ h,
                                                        const int* __restrict__ off,
                                                        const int* __restrict__ csr,
                                                        f16* __restrict__ mean, int N) {
    int n = blockIdx.x * 4 + (threadIdx.x >> 6);
    int l = threadIdx.x & 63;
    if (n >= N) return;
    int s = off[n], e = off[n + 1];
    const f16x2* h2 = (const f16x2*)h;
    float a0 = 0.f, a1 = 0.f;
    for (int i = s; i < e; ++i) {
        f16x2 v = h2[csr[i] * 64 + l];
        a0 += (float)v[0];
        a1 += (float)v[1];
    }
    int deg = e - s;
    float inv = 1.0f / (float)(deg > 0 ? deg : 1);
    f16x2 o;
    o[0] = (f16)(a0 * inv);
    o[1] = (f16)(a1 * inv);
    ((f16x2*)mean)[n * 64 + l] = o;
}

// ---------------- MFMA GEMM: OUT = act(A @ W1^T + bias [+ B @ W2^T]) ----------------
// A,B: [M,128] (fp32 or f16), W (f16, row-major [col][k]), OUT: [M,128]
// Block: 128 rows x 128 cols, 4 waves; wave w owns rows [w*32, w*32+32).
// mfma_f32_16x16x32_f16: A frag lane l -> A[row=l&15][k=(l>>4)*8+j] (8 contig f16)
//                        B frag lane l -> W[col=l&15][k=(l>>4)*8+j] (8 contig f16)
//                        D lane l reg j -> D[row=(l>>4)*4+j][col=l&15]

template <typename T>
__device__ inline v8h load_frag(const T* __restrict__ A, int row, int kb, int M) {
    if (row >= M) {
        v8h z = {};
        return z;
    }
    if constexpr (sizeof(T) == 2) {
        return *(const v8h*)(A + row * DD + kb);
    } else {
        float4 a = *(const float4*)(A + row * DD + kb);
        float4 b = *(const float4*)(A + row * DD + kb + 4);
        v8h r;
        r[0] = (f16)a.x; r[1] = (f16)a.y; r[2] = (f16)a.z; r[3] = (f16)a.w;
        r[4] = (f16)b.x; r[5] = (f16)b.y; r[6] = (f16)b.z; r[7] = (f16)b.w;
        return r;
    }
}

// Stage 128x128 f16 W into LDS, chunk-swizzled: chunk (16B) sc = c16 ^ (col&7)
__device__ inline void stage_w(const f16* __restrict__ Wg, f16* __restrict__ smem, int t) {
#pragma unroll
    for (int i = 0; i < 8; ++i) {
        int idx16 = i * 256 + t;
        int col = idx16 >> 4, c16 = idx16 & 15;
        int sc = c16 ^ (col & 7);
        uint4 v = *(const uint4*)(Wg + idx16 * 8);
        *(uint4*)(smem + col * DD + sc * 8) = v;
    }
}

__device__ inline v8h read_b(const f16* __restrict__ smem, int ct, int ki, int l) {
    int col = ct * 16 + (l & 15);
    int c16 = ki * 4 + (l >> 4);
    int sc = c16 ^ (col & 7);
    return *(const v8h*)(smem + col * DD + sc * 8);
}

template <typename TA, typename TB, typename TO, bool RELU, bool HASB>
__global__ __launch_bounds__(256) void mgemm(const TA* __restrict__ A,
                                             const f16* __restrict__ W1,
                                             const float* __restrict__ bias,
                                             const TB* __restrict__ B,
                                             const f16* __restrict__ W2,
                                             TO* __restrict__ OUT, int M) {
    __shared__ f16 WS[DD * DD];
    int t = threadIdx.x, l = t & 63, w = t >> 6;
    int row0 = blockIdx.x * 128 + w * 32;

    f32x4 acc[2][8];
#pragma unroll
    for (int ct = 0; ct < 8; ++ct) {
        float bv = bias[ct * 16 + (l & 15)];
        f32x4 b4 = {bv, bv, bv, bv};
        acc[0][ct] = b4;
        acc[1][ct] = b4;
    }

    stage_w(W1, WS, t);
    v8h af[2][4];
#pragma unroll
    for (int rt = 0; rt < 2; ++rt)
#pragma unroll
        for (int ki = 0; ki < 4; ++ki)
            af[rt][ki] = load_frag(A, row0 + rt * 16 + (l & 15), ki * 32 + (l >> 4) * 8, M);
    __syncthreads();

#pragma unroll
    for (int ct = 0; ct < 8; ++ct)
#pragma unroll
        for (int ki = 0; ki < 4; ++ki) {
            v8h b = read_b(WS, ct, ki, l);
            acc[0][ct] = __builtin_amdgcn_mfma_f32_16x16x32_f16(af[0][ki], b, acc[0][ct], 0, 0, 0);
            acc[1][ct] = __builtin_amdgcn_mfma_f32_16x16x32_f16(af[1][ki], b, acc[1][ct], 0, 0, 0);
        }

    if constexpr (HASB) {
        __syncthreads();  // all waves done reading W1
        stage_w(W2, WS, t);
#pragma unroll
        for (int rt = 0; rt < 2; ++rt)
#pragma unroll
            for (int ki = 0; ki < 4; ++ki)
                af[rt][ki] = load_frag(B, row0 + rt * 16 + (l & 15), ki * 32 + (l >> 4) * 8, M);
        __syncthreads();
#pragma unroll
        for (int ct = 0; ct < 8; ++ct)
#pragma unroll
            for (int ki = 0; ki < 4; ++ki) {
                v8h b = read_b(WS, ct, ki, l);
                acc[0][ct] = __builtin_amdgcn_mfma_f32_16x16x32_f16(af[0][ki], b, acc[0][ct], 0, 0, 0);
                acc[1][ct] = __builtin_amdgcn_mfma_f32_16x16x32_f16(af[1][ki], b, acc[1][ct], 0, 0, 0);
            }
    }

    // epilogue: D[row=(l>>4)*4+j][col=l&15]
#pragma unroll
    for (int rt = 0; rt < 2; ++rt)
#pragma unroll
        for (int ct = 0; ct < 8; ++ct)
#pragma unroll
            for (int j = 0; j < 4; ++j) {
                int row = row0 + rt * 16 + (l >> 4) * 4 + j;
                if (row < M) {
                    float v = acc[rt][ct][j];
                    if (RELU) v = fmaxf(v, 0.f);
                    OUT[row * DD + ct * 16 + (l & 15)] = (TO)v;
                }
            }
}

// ---------------- launch ----------------

extern "C" void kernel_launch(void* const* d_in, const int* in_sizes, int n_in,
                              void* d_out, int out_size, void* d_ws, size_t ws_size,
                              hipStream_t stream) {
    const float* x = (const float*)d_in[0];
    const int* ei = (const int*)d_in[1];
    const float* Wp0 = (const float*)d_in[2];
    const float* bp0 = (const float*)d_in[3];
    const float* Wl0 = (const float*)d_in[4];
    const float* bl0 = (const float*)d_in[5];
    const float* Wr0 = (const float*)d_in[6];
    const float* Wp1 = (const float*)d_in[7];
    const float* bp1 = (const float*)d_in[8];
    const float* Wl1 = (const float*)d_in[9];
    const float* bl1 = (const float*)d_in[10];
    const float* Wr1 = (const float*)d_in[11];

    int N = in_sizes[0] / DD;
    int E = in_sizes[1] / 2;
    const int* src = ei;
    const int* dst = ei + E;

    // ---- workspace layout (respect ws_size!) ----
    // small buffers first, then the two f16 node buffers; h lives in d_out's
    // lower half (f16, N*128*2 = 25.6MB < out bytes/2) and is dead before the
    // final GEMM rewrites all of d_out. Total ws use ~54.8MB (was 80.2MB,
    // which risked overflowing ws_size -> cross-replay corruption).
    char* ws = (char*)d_ws;
    size_t o = 0;
    auto alloc = [&](size_t bytes) {
        size_t r = o;
        o = (o + bytes + 255) & ~(size_t)255;
        return r;
    };
    f16* w16 = (f16*)(ws + alloc((size_t)6 * DD * DD * 2));
    int* cnt = (int*)(ws + alloc((size_t)N * 4));
    int* off = (int*)(ws + alloc((size_t)(N + 1) * 4));
    int NB = cdiv(N, 256);
    int* bsum = (int*)(ws + alloc((size_t)NB * 4));
    int* boff = (int*)(ws + alloc((size_t)NB * 4));
    int* csr = (int*)(ws + alloc((size_t)E * 4));
    f16* mean = (f16*)(ws + alloc((size_t)N * DD * 2));
    f16* y1 = (f16*)(ws + alloc((size_t)N * DD * 2));
    f16* h = (f16*)d_out;  // lower half of d_out, rewritten by final GEMM
    (void)ws_size;

    // CSR build (shared by both layers)
    zero_kernel<<<NB, 256, 0, stream>>>(cnt, N);
    count_kernel<<<cdiv(E, 256), 256, 0, stream>>>(dst, E, cnt);
    scan1<<<NB, 256, 0, stream>>>(cnt, N, bsum);
    scan2<<<1, 512, 0, stream>>>(bsum, NB, boff);
    scan3<<<NB, 256, 0, stream>>>(cnt, boff, N, off);
    fill_kernel<<<cdiv(E, 256), 256, 0, stream>>>(src, dst, E, off, cnt, csr);

    // weights -> f16 once: order [Wp0, Wl0, Wr0, Wp1, Wl1, Wr1]
    cvt_w_kernel<<<96, 256, 0, stream>>>(Wp0, Wl0, Wr0, Wp1, Wl1, Wr1, w16);
    const f16* wp0 = w16 + 0 * 16384;
    const f16* wl0 = w16 + 1 * 16384;
    const f16* wr0 = w16 + 2 * 16384;
    const f16* wp1 = w16 + 3 * 16384;
    const f16* wl1 = w16 + 4 * 16384;
    const f16* wr1 = w16 + 5 * 16384;

    int GB = cdiv(N, 128);
    // layer 1
    mgemm<float, f16, f16, true, false>
        <<<GB, 256, 0, stream>>>(x, wp0, bp0, nullptr, nullptr, h, N);
    aggregate_kernel<<<cdiv(N, 4), 256, 0, stream>>>(h, off, csr, mean, N);
    mgemm<f16, float, f16, true, true>
        <<<GB, 256, 0, stream>>>(mean, wl0, bl0, x, wr0, y1, N);
    // layer 2
    mgemm<f16, f16, f16, true, false>
        <<<GB, 256, 0, stream>>>(y1, wp1, bp1, nullptr, nullptr, h, N);
    aggregate_kernel<<<cdiv(N, 4), 256, 0, stream>>>(h, off, csr, mean, N);
    mgemm<f16, f16, float, false, true>
        <<<GB, 256, 0, stream>>>(mean, wl1, bl1, y1, wr1, (float*)d_out, N);
}

// Round 4
// 234.710 us; speedup vs baseline: 5.2848x; 1.2608x over previous
//
#include <hip/hip_runtime.h>

#define DD 128

typedef _Float16 f16;
typedef __attribute__((ext_vector_type(8))) _Float16 v8h;
typedef __attribute__((ext_vector_type(4))) _Float16 v4h;
typedef __attribute__((ext_vector_type(2))) _Float16 f16x2;
typedef __attribute__((ext_vector_type(4))) float f32x4;

static inline int cdiv(int a, int b) { return (a + b - 1) / b; }

// ---------------- small utility ----------------

__global__ __launch_bounds__(256) void zero_kernel(int* __restrict__ p, int n) {
    int i = blockIdx.x * 256 + threadIdx.x;
    if (i < n) p[i] = 0;
}

// ---------------- CSR build ----------------

__global__ __launch_bounds__(256) void count_kernel(const int* __restrict__ dst, int E,
                                                    int* __restrict__ cnt) {
    int e = blockIdx.x * 256 + threadIdx.x;
    if (e < E) atomicAdd(&cnt[dst[e]], 1);
}

__global__ __launch_bounds__(256) void scan1(const int* __restrict__ cnt, int N,
                                             int* __restrict__ bsum) {
    __shared__ int s[256];
    int i = blockIdx.x * 256 + threadIdx.x;
    s[threadIdx.x] = (i < N) ? cnt[i] : 0;
    __syncthreads();
    for (int off = 128; off > 0; off >>= 1) {
        if (threadIdx.x < off) s[threadIdx.x] += s[threadIdx.x + off];
        __syncthreads();
    }
    if (threadIdx.x == 0) bsum[blockIdx.x] = s[0];
}

__global__ __launch_bounds__(512) void scan2(const int* __restrict__ bsum, int NB,
                                             int* __restrict__ boff) {
    __shared__ int s[512];
    int t = threadIdx.x;
    int v = (t < NB) ? bsum[t] : 0;
    s[t] = v;
    __syncthreads();
    for (int off = 1; off < 512; off <<= 1) {
        int x = (t >= off) ? s[t - off] : 0;
        __syncthreads();
        s[t] += x;
        __syncthreads();
    }
    if (t < NB) boff[t] = s[t] - v;  // exclusive
}

__global__ __launch_bounds__(256) void scan3(const int* __restrict__ cnt,
                                             const int* __restrict__ boff, int N,
                                             int* __restrict__ off) {
    __shared__ int s[256];
    int t = threadIdx.x;
    int i = blockIdx.x * 256 + t;
    int v = (i < N) ? cnt[i] : 0;
    s[t] = v;
    __syncthreads();
    for (int o = 1; o < 256; o <<= 1) {
        int x = (t >= o) ? s[t - o] : 0;
        __syncthreads();
        s[t] += x;
        __syncthreads();
    }
    int excl = s[t] - v + boff[blockIdx.x];
    if (i < N) off[i] = excl;
    if (i == N - 1) off[N] = excl + v;
}

__global__ __launch_bounds__(256) void fill_kernel(const int* __restrict__ src,
                                                   const int* __restrict__ dst, int E,
                                                   const int* __restrict__ off,
                                                   int* __restrict__ cnt,
                                                   int* __restrict__ csr) {
    int e = blockIdx.x * 256 + threadIdx.x;
    if (e < E) {
        int d = dst[e];
        int p = atomicSub(&cnt[d], 1) - 1;  // unique slot within [0, deg)
        csr[off[d] + p] = src[e];
    }
}

// ---------------- fp32 -> f16 conversions ----------------

__global__ __launch_bounds__(256) void cvt_w_kernel(const float* __restrict__ W0,
                                                    const float* __restrict__ W1,
                                                    const float* __restrict__ W2,
                                                    const float* __restrict__ W3,
                                                    const float* __restrict__ W4,
                                                    const float* __restrict__ W5,
                                                    f16* __restrict__ out) {
    int mat = blockIdx.x >> 4;  // 16 blocks per matrix (16384 elems / (256*4))
    const float* W = mat == 0 ? W0 : mat == 1 ? W1 : mat == 2 ? W2
                   : mat == 3 ? W3 : mat == 4 ? W4 : W5;
    int base = (blockIdx.x & 15) * 1024 + threadIdx.x * 4;
    float4 v = *(const float4*)(W + base);
    v4h o;
    o[0] = (f16)v.x; o[1] = (f16)v.y; o[2] = (f16)v.z; o[3] = (f16)v.w;
    *(v4h*)(out + mat * 16384 + base) = o;
}

__global__ __launch_bounds__(256) void cvt_x_kernel(const float* __restrict__ x,
                                                    f16* __restrict__ out, int n8) {
    int i = blockIdx.x * 256 + threadIdx.x;
    if (i >= n8) return;
    float4 a = *(const float4*)(x + (size_t)i * 8);
    float4 b = *(const float4*)(x + (size_t)i * 8 + 4);
    v8h r;
    r[0] = (f16)a.x; r[1] = (f16)a.y; r[2] = (f16)a.z; r[3] = (f16)a.w;
    r[4] = (f16)b.x; r[5] = (f16)b.y; r[6] = (f16)b.z; r[7] = (f16)b.w;
    *(v8h*)(out + (size_t)i * 8) = r;
}

// ---------------- aggregation: mean of gathered h rows ----------------
// Wave per node; 4 groups x 16 lanes; each group gathers a full 256B row
// (16 lanes x 16B), groups stride the edge list by 4 -> 4 rows in flight.

__global__ __launch_bounds__(256) void aggregate_kernel(const f16* __restrict__ h,
                                                        const int* __restrict__ off,
                                                        const int* __restrict__ csr,
                                                        f16* __restrict__ mean, int N) {
    int n = blockIdx.x * 4 + (threadIdx.x >> 6);
    int l = threadIdx.x & 63;
    int g = l >> 4, c = l & 15;
    if (n >= N) return;
    int s = off[n], e = off[n + 1];
    float acc[8] = {0.f, 0.f, 0.f, 0.f, 0.f, 0.f, 0.f, 0.f};
    for (int i = s + g; i < e; i += 4) {
        int idx = csr[i];
        v8h v = *(const v8h*)(h + (size_t)idx * DD + c * 8);
#pragma unroll
        for (int j = 0; j < 8; ++j) acc[j] += (float)v[j];
    }
    // reduce across the 4 groups (lanes l, l^16, l^32, l^48)
#pragma unroll
    for (int j = 0; j < 8; ++j) {
        acc[j] += __shfl_xor(acc[j], 16);
        acc[j] += __shfl_xor(acc[j], 32);
    }
    int deg = e - s;
    float inv = 1.0f / (float)(deg > 0 ? deg : 1);
    if (g == 0) {
        v8h o;
#pragma unroll
        for (int j = 0; j < 8; ++j) o[j] = (f16)(acc[j] * inv);
        *(v8h*)(mean + (size_t)n * DD + c * 8) = o;
    }
}

// ---------------- MFMA GEMM: OUT = act(A @ W1^T + bias [+ B @ W2^T]) ----------------
// A,B: [M,128] f16, W (f16, row-major [col][k]), OUT: [M,128]
// Block: 128 rows x 128 cols, 4 waves; wave w owns rows [w*32, w*32+32).
// mfma_f32_16x16x32_f16: A frag lane l -> A[row=l&15][k=(l>>4)*8+j] (8 contig f16)
//                        B frag lane l -> W[col=l&15][k=(l>>4)*8+j] (8 contig f16)
//                        D lane l reg j -> D[row=(l>>4)*4+j][col=l&15]

__device__ inline v8h load_frag(const f16* __restrict__ A, int row, int kb, int M) {
    if (row >= M) {
        v8h z = {};
        return z;
    }
    return *(const v8h*)(A + (size_t)row * DD + kb);
}

// Stage 128x128 f16 W into LDS, chunk-swizzled: chunk (16B) sc = c16 ^ (col&7)
__device__ inline void stage_w(const f16* __restrict__ Wg, f16* __restrict__ smem, int t) {
#pragma unroll
    for (int i = 0; i < 8; ++i) {
        int idx16 = i * 256 + t;
        int col = idx16 >> 4, c16 = idx16 & 15;
        int sc = c16 ^ (col & 7);
        uint4 v = *(const uint4*)(Wg + idx16 * 8);
        *(uint4*)(smem + col * DD + sc * 8) = v;
    }
}

__device__ inline v8h read_b(const f16* __restrict__ smem, int ct, int ki, int l) {
    int col = ct * 16 + (l & 15);
    int c16 = ki * 4 + (l >> 4);
    int sc = c16 ^ (col & 7);
    return *(const v8h*)(smem + col * DD + sc * 8);
}

template <typename TO, bool RELU, bool HASB>
__global__ __launch_bounds__(256) void mgemm(const f16* __restrict__ A,
                                             const f16* __restrict__ W1,
                                             const float* __restrict__ bias,
                                             const f16* __restrict__ B,
                                             const f16* __restrict__ W2,
                                             TO* __restrict__ OUT, int M) {
    __shared__ f16 WS[DD * DD];
    int t = threadIdx.x, l = t & 63, w = t >> 6;
    int row0 = blockIdx.x * 128 + w * 32;

    f32x4 acc[2][8];
#pragma unroll
    for (int ct = 0; ct < 8; ++ct) {
        float bv = bias[ct * 16 + (l & 15)];
        f32x4 b4 = {bv, bv, bv, bv};
        acc[0][ct] = b4;
        acc[1][ct] = b4;
    }

    stage_w(W1, WS, t);
    v8h af[2][4];
#pragma unroll
    for (int rt = 0; rt < 2; ++rt)
#pragma unroll
        for (int ki = 0; ki < 4; ++ki)
            af[rt][ki] = load_frag(A, row0 + rt * 16 + (l & 15), ki * 32 + (l >> 4) * 8, M);
    __syncthreads();

#pragma unroll
    for (int ct = 0; ct < 8; ++ct)
#pragma unroll
        for (int ki = 0; ki < 4; ++ki) {
            v8h b = read_b(WS, ct, ki, l);
            acc[0][ct] = __builtin_amdgcn_mfma_f32_16x16x32_f16(af[0][ki], b, acc[0][ct], 0, 0, 0);
            acc[1][ct] = __builtin_amdgcn_mfma_f32_16x16x32_f16(af[1][ki], b, acc[1][ct], 0, 0, 0);
        }

    if constexpr (HASB) {
        __syncthreads();  // all waves done reading W1
        stage_w(W2, WS, t);
#pragma unroll
        for (int rt = 0; rt < 2; ++rt)
#pragma unroll
            for (int ki = 0; ki < 4; ++ki)
                af[rt][ki] = load_frag(B, row0 + rt * 16 + (l & 15), ki * 32 + (l >> 4) * 8, M);
        __syncthreads();
#pragma unroll
        for (int ct = 0; ct < 8; ++ct)
#pragma unroll
            for (int ki = 0; ki < 4; ++ki) {
                v8h b = read_b(WS, ct, ki, l);
                acc[0][ct] = __builtin_amdgcn_mfma_f32_16x16x32_f16(af[0][ki], b, acc[0][ct], 0, 0, 0);
                acc[1][ct] = __builtin_amdgcn_mfma_f32_16x16x32_f16(af[1][ki], b, acc[1][ct], 0, 0, 0);
            }
    }

    // epilogue: D[row=(l>>4)*4+j][col=l&15]
#pragma unroll
    for (int rt = 0; rt < 2; ++rt)
#pragma unroll
        for (int ct = 0; ct < 8; ++ct)
#pragma unroll
            for (int j = 0; j < 4; ++j) {
                int row = row0 + rt * 16 + (l >> 4) * 4 + j;
                if (row < M) {
                    float v = acc[rt][ct][j];
                    if (RELU) v = fmaxf(v, 0.f);
                    OUT[(size_t)row * DD + ct * 16 + (l & 15)] = (TO)v;
                }
            }
}

// ---------------- launch ----------------

extern "C" void kernel_launch(void* const* d_in, const int* in_sizes, int n_in,
                              void* d_out, int out_size, void* d_ws, size_t ws_size,
                              hipStream_t stream) {
    const float* x = (const float*)d_in[0];
    const int* ei = (const int*)d_in[1];
    const float* Wp0 = (const float*)d_in[2];
    const float* bp0 = (const float*)d_in[3];
    const float* Wl0 = (const float*)d_in[4];
    const float* bl0 = (const float*)d_in[5];
    const float* Wr0 = (const float*)d_in[6];
    const float* Wp1 = (const float*)d_in[7];
    const float* bp1 = (const float*)d_in[8];
    const float* Wl1 = (const float*)d_in[9];
    const float* bl1 = (const float*)d_in[10];
    const float* Wr1 = (const float*)d_in[11];

    int N = in_sizes[0] / DD;
    int E = in_sizes[1] / 2;
    const int* src = ei;
    const int* dst = ei + E;

    // ---- workspace layout (~54.8MB; h and x16 live in d_out) ----
    // d_out (51.2MB fp32) timeline: [h: lower 25.6MB][x16: upper 25.6MB];
    // x16 dead after gemm2, h dead after agg2; final GEMM rewrites all of
    // d_out reading only mean/y1 (in ws).
    char* ws = (char*)d_ws;
    size_t o = 0;
    auto alloc = [&](size_t bytes) {
        size_t r = o;
        o = (o + bytes + 255) & ~(size_t)255;
        return r;
    };
    f16* w16 = (f16*)(ws + alloc((size_t)6 * DD * DD * 2));
    int* cnt = (int*)(ws + alloc((size_t)N * 4));
    int* off = (int*)(ws + alloc((size_t)(N + 1) * 4));
    int NB = cdiv(N, 256);
    int* bsum = (int*)(ws + alloc((size_t)NB * 4));
    int* boff = (int*)(ws + alloc((size_t)NB * 4));
    int* csr = (int*)(ws + alloc((size_t)E * 4));
    f16* mean = (f16*)(ws + alloc((size_t)N * DD * 2));
    f16* y1 = (f16*)(ws + alloc((size_t)N * DD * 2));
    f16* h = (f16*)d_out;                                    // lower half of d_out
    f16* x16 = (f16*)((char*)d_out + (size_t)N * DD * 2);    // upper half of d_out
    (void)ws_size;

    // CSR build (shared by both layers)
    zero_kernel<<<NB, 256, 0, stream>>>(cnt, N);
    count_kernel<<<cdiv(E, 256), 256, 0, stream>>>(dst, E, cnt);
    scan1<<<NB, 256, 0, stream>>>(cnt, N, bsum);
    scan2<<<1, 512, 0, stream>>>(bsum, NB, boff);
    scan3<<<NB, 256, 0, stream>>>(cnt, boff, N, off);
    fill_kernel<<<cdiv(E, 256), 256, 0, stream>>>(src, dst, E, off, cnt, csr);

    // weights -> f16 once: order [Wp0, Wl0, Wr0, Wp1, Wl1, Wr1]
    cvt_w_kernel<<<96, 256, 0, stream>>>(Wp0, Wl0, Wr0, Wp1, Wl1, Wr1, w16);
    const f16* wp0 = w16 + 0 * 16384;
    const f16* wl0 = w16 + 1 * 16384;
    const f16* wr0 = w16 + 2 * 16384;
    const f16* wp1 = w16 + 3 * 16384;
    const f16* wl1 = w16 + 4 * 16384;
    const f16* wr1 = w16 + 5 * 16384;

    // x -> f16 once (same precision as before: fp32 path also cast to f16)
    cvt_x_kernel<<<cdiv(N * DD / 8, 256), 256, 0, stream>>>(x, x16, N * DD / 8);

    int GB = cdiv(N, 128);
    // layer 1
    mgemm<f16, true, false>
        <<<GB, 256, 0, stream>>>(x16, wp0, bp0, nullptr, nullptr, h, N);
    aggregate_kernel<<<cdiv(N, 4), 256, 0, stream>>>(h, off, csr, mean, N);
    mgemm<f16, true, true>
        <<<GB, 256, 0, stream>>>(mean, wl0, bl0, x16, wr0, y1, N);
    // layer 2
    mgemm<f16, true, false>
        <<<GB, 256, 0, stream>>>(y1, wp1, bp1, nullptr, nullptr, h, N);
    aggregate_kernel<<<cdiv(N, 4), 256, 0, stream>>>(h, off, csr, mean, N);
    mgemm<float, false, true>
        <<<GB, 256, 0, stream>>>(mean, wl1, bl1, y1, wr1, (float*)d_out, N);
}